// Round 1
// baseline (1497.949 us; speedup 1.0000x reference)
//
#include <hip/hip_runtime.h>
#include <hip/hip_bf16.h>
#include <math.h>

// Problem constants (feature dims fixed by the reference).
#define IN_DIM 128
#define HID_DIM 128
#define OUT_DIM 64
#define NCLS 7

// ---------------------------------------------------------------------------
// K1: F0 = x @ W1   [N,128] = [N,128]@[128,128]
// Block: 256 threads, 64 rows per block. x tile staged in LDS; W1 streamed
// from global (L2-resident, coalesced 256B per wave).
// ---------------------------------------------------------------------------
__global__ __launch_bounds__(256) void gemm1_kernel(
    const float* __restrict__ x, const float* __restrict__ W1,
    float* __restrict__ F0, int n) {
  __shared__ float xs[64 * 128];  // 32KB
  const int t = threadIdx.x;
  const int n0 = blockIdx.x * 64;

  // Load 64 rows of x (guard + zero-pad).
  for (int i = t; i < 64 * 128; i += 256) {
    int r = i >> 7, cc = i & 127;
    int gr = n0 + r;
    xs[i] = (gr < n) ? x[(size_t)gr * 128 + cc] : 0.0f;
  }
  __syncthreads();

  const int c = t & 127;
  const int half = t >> 7;  // 0 or 1
  float acc[32];
#pragma unroll
  for (int i = 0; i < 32; i++) acc[i] = 0.0f;

  for (int k0 = 0; k0 < 128; k0 += 8) {
    float w[8];
#pragma unroll
    for (int kk = 0; kk < 8; kk++) w[kk] = W1[(size_t)(k0 + kk) * 128 + c];
#pragma unroll
    for (int i = 0; i < 32; i++) {
      const int r = half + 2 * i;
#pragma unroll
      for (int kk = 0; kk < 8; kk++) acc[i] += xs[r * 128 + k0 + kk] * w[kk];
    }
  }
#pragma unroll
  for (int i = 0; i < 32; i++) {
    int gr = n0 + half + 2 * i;
    if (gr < n) F0[(size_t)gr * 128 + c] = acc[i];
  }
}

// ---------------------------------------------------------------------------
// K2: per-node attention dots: as_dot[n]=F0[n]·a_src, ad_dot[n]=F0[n]·a_dst
// One wave (64 lanes) per node.
// ---------------------------------------------------------------------------
__global__ __launch_bounds__(256) void dots_kernel(
    const float* __restrict__ F0, const float* __restrict__ a_src,
    const float* __restrict__ a_dst, float* __restrict__ as_dot,
    float* __restrict__ ad_dot, int n) {
  const int wid = (blockIdx.x * blockDim.x + threadIdx.x) >> 6;
  const int lane = threadIdx.x & 63;
  if (wid >= n) return;
  float f0 = F0[(size_t)wid * 128 + lane];
  float f1 = F0[(size_t)wid * 128 + 64 + lane];
  float s = f0 * a_src[lane] + f1 * a_src[64 + lane];
  float d = f0 * a_dst[lane] + f1 * a_dst[64 + lane];
  for (int m = 32; m; m >>= 1) {
    s += __shfl_xor(s, m);
    d += __shfl_xor(d, m);
  }
  if (lane == 0) {
    as_dot[wid] = s;
    ad_dot[wid] = d;
  }
}

// ---------------------------------------------------------------------------
// K3: degree histogram over dst
// ---------------------------------------------------------------------------
__global__ __launch_bounds__(256) void hist_kernel(const int* __restrict__ dst,
                                                   int* __restrict__ deg,
                                                   int e) {
  int i = blockIdx.x * blockDim.x + threadIdx.x;
  if (i < e) atomicAdd(&deg[dst[i]], 1);
}

// ---------------------------------------------------------------------------
// K4: single-block exclusive scan of deg -> rowptr (and cursor copy).
// 1024 threads, `items` contiguous elements each.
// ---------------------------------------------------------------------------
__global__ __launch_bounds__(1024) void scan_kernel(
    const int* __restrict__ deg, int* __restrict__ rowptr,
    int* __restrict__ cursor, int n, int items) {
  __shared__ int lds[1024];
  const int t = threadIdx.x;
  const int b = t * items;
  const int e = min(b + items, n);
  int s = 0;
  for (int i = b; i < e; i++) s += deg[i];
  lds[t] = s;
  __syncthreads();
  for (int off = 1; off < 1024; off <<= 1) {
    int add = (t >= off) ? lds[t - off] : 0;
    __syncthreads();
    lds[t] += add;
    __syncthreads();
  }
  int run = lds[t] - s;  // exclusive prefix of this thread's chunk
  for (int i = b; i < e; i++) {
    rowptr[i] = run;
    cursor[i] = run;
    run += deg[i];
  }
  if (t == 1023) rowptr[n] = lds[1023];
}

// ---------------------------------------------------------------------------
// K5: scatter edges into CSR slots (store src per slot).
// ---------------------------------------------------------------------------
__global__ __launch_bounds__(256) void scatter_kernel(
    const int* __restrict__ src, const int* __restrict__ dst,
    int* __restrict__ cursor, int* __restrict__ esrc, int e) {
  int i = blockIdx.x * blockDim.x + threadIdx.x;
  if (i < e) {
    int pos = atomicAdd(&cursor[dst[i]], 1);
    esrc[pos] = src[i];
  }
}

// ---------------------------------------------------------------------------
// K6: GAT layer 1. One wave per dst node: segment softmax (max, sum) over its
// edges, write alpha (B0) per CSR slot, gather alpha*F0[src] -> Z0 (+b1).
// ---------------------------------------------------------------------------
__global__ __launch_bounds__(256) void gat1_kernel(
    const float* __restrict__ F0, const float* __restrict__ as_dot,
    const float* __restrict__ ad_dot, const int* __restrict__ rowptr,
    const int* __restrict__ esrc, const float* __restrict__ b1,
    float* __restrict__ alpha, float* __restrict__ Z0out, int n) {
  const int wid = (blockIdx.x * blockDim.x + threadIdx.x) >> 6;
  const int lane = threadIdx.x & 63;
  if (wid >= n) return;
  const int start = rowptr[wid];
  const int end = rowptr[wid + 1];
  const float adn = ad_dot[wid];

  // pass A: max
  float lmax = -INFINITY;
  for (int j = start + lane; j < end; j += 64) {
    int s = esrc[j];
    float z = as_dot[s] + adn;
    z = (z > 0.0f) ? z : 0.2f * z;
    lmax = fmaxf(lmax, z);
  }
  for (int m = 32; m; m >>= 1) lmax = fmaxf(lmax, __shfl_xor(lmax, m));

  // pass B: sum of exp
  float lsum = 0.0f;
  for (int j = start + lane; j < end; j += 64) {
    int s = esrc[j];
    float z = as_dot[s] + adn;
    z = (z > 0.0f) ? z : 0.2f * z;
    lsum += expf(z - lmax);
  }
  for (int m = 32; m; m >>= 1) lsum += __shfl_xor(lsum, m);
  const float inv = 1.0f / (lsum + 1e-16f);

  // pass C: alpha + feature gather
  float acc0 = 0.0f, acc1 = 0.0f;
  for (int base = start; base < end; base += 64) {
    const int len = min(64, end - base);
    float aj = 0.0f;
    int sj = 0;
    if (lane < len) {
      int j = base + lane;
      sj = esrc[j];
      float z = as_dot[sj] + adn;
      z = (z > 0.0f) ? z : 0.2f * z;
      aj = expf(z - lmax) * inv;
      alpha[j] = aj;
    }
    for (int q = 0; q < len; q++) {
      float a = __shfl(aj, q);
      int s = __shfl(sj, q);
      acc0 += a * F0[(size_t)s * 128 + lane];
      acc1 += a * F0[(size_t)s * 128 + 64 + lane];
    }
  }
  Z0out[(size_t)wid * 128 + lane] = acc0 + b1[lane];
  Z0out[(size_t)wid * 128 + 64 + lane] = acc1 + b1[64 + lane];
}

// ---------------------------------------------------------------------------
// K7: per-class sums of Z0 (block-local register accumulation, then atomics).
// Block = 128 threads (one feature each); 1024 nodes per block.
// ---------------------------------------------------------------------------
#define CB_NODES 1024
__global__ __launch_bounds__(128) void centroid_sum_kernel(
    const float* __restrict__ Z0out, const int* __restrict__ y,
    float* __restrict__ csum, float* __restrict__ ccnt, int n) {
  const int t = threadIdx.x;  // 0..127
  const int n0 = blockIdx.x * CB_NODES;
  const int n1 = min(n0 + CB_NODES, n);
  float a0 = 0, a1 = 0, a2 = 0, a3 = 0, a4 = 0, a5 = 0, a6 = 0;
  int c0 = 0, c1 = 0, c2 = 0, c3 = 0, c4 = 0, c5 = 0, c6 = 0;
  for (int i = n0; i < n1; i++) {
    const int c = y[i];
    const float v = Z0out[(size_t)i * 128 + t];
    a0 += (c == 0) ? v : 0.0f;
    a1 += (c == 1) ? v : 0.0f;
    a2 += (c == 2) ? v : 0.0f;
    a3 += (c == 3) ? v : 0.0f;
    a4 += (c == 4) ? v : 0.0f;
    a5 += (c == 5) ? v : 0.0f;
    a6 += (c == 6) ? v : 0.0f;
    if (t == 0) {
      c0 += (c == 0); c1 += (c == 1); c2 += (c == 2); c3 += (c == 3);
      c4 += (c == 4); c5 += (c == 5); c6 += (c == 6);
    }
  }
  atomicAdd(&csum[0 * 128 + t], a0);
  atomicAdd(&csum[1 * 128 + t], a1);
  atomicAdd(&csum[2 * 128 + t], a2);
  atomicAdd(&csum[3 * 128 + t], a3);
  atomicAdd(&csum[4 * 128 + t], a4);
  atomicAdd(&csum[5 * 128 + t], a5);
  atomicAdd(&csum[6 * 128 + t], a6);
  if (t == 0) {
    atomicAdd(&ccnt[0], (float)c0);
    atomicAdd(&ccnt[1], (float)c1);
    atomicAdd(&ccnt[2], (float)c2);
    atomicAdd(&ccnt[3], (float)c3);
    atomicAdd(&ccnt[4], (float)c4);
    atomicAdd(&ccnt[5], (float)c5);
    atomicAdd(&ccnt[6], (float)c6);
  }
}

__global__ __launch_bounds__(128) void centroid_fin_kernel(
    const float* __restrict__ csum, const float* __restrict__ ccnt,
    float* __restrict__ ca) {
  const int k = blockIdx.x;
  const int t = threadIdx.x;
  ca[k * 128 + t] = csum[k * 128 + t] / (ccnt[k] + 1e-12f);
}

// ---------------------------------------------------------------------------
// K9: phi_Z, phi_X, S, diff, v. One wave per node.
// v[d] = sum_k coef_k * (Z0[d]-C_a[k][d]),
// coef_k = -(w_k - W*phi_k)/(dist_k+1e-12), w_k = phi_k*diff_k.
// ---------------------------------------------------------------------------
__global__ __launch_bounds__(256) void phi_v_kernel(
    const float* __restrict__ Z0out, const float* __restrict__ x,
    const float* __restrict__ ca, const float* __restrict__ cb,
    const float* __restrict__ Q, const int* __restrict__ y,
    float* __restrict__ vbuf, float* __restrict__ phi_out, int n) {
  const int wid = (blockIdx.x * blockDim.x + threadIdx.x) >> 6;
  const int lane = threadIdx.x & 63;
  if (wid >= n) return;
  const float z0 = Z0out[(size_t)wid * 128 + lane];
  const float z1 = Z0out[(size_t)wid * 128 + 64 + lane];
  const float x0 = x[(size_t)wid * 128 + lane];
  const float x1 = x[(size_t)wid * 128 + 64 + lane];

  float sZ[NCLS], sX[NCLS];
#pragma unroll
  for (int k = 0; k < NCLS; k++) {
    float d0 = z0 - ca[k * 128 + lane];
    float d1 = z1 - ca[k * 128 + 64 + lane];
    sZ[k] = d0 * d0 + d1 * d1;
    float e0 = x0 - cb[k * 128 + lane];
    float e1 = x1 - cb[k * 128 + 64 + lane];
    sX[k] = e0 * e0 + e1 * e1;
  }
  for (int m = 32; m; m >>= 1) {
#pragma unroll
    for (int k = 0; k < NCLS; k++) {
      sZ[k] += __shfl_xor(sZ[k], m);
      sX[k] += __shfl_xor(sX[k], m);
    }
  }
  // all lanes redundantly compute the scalar chain
  float distZ[NCLS], phiZ[NCLS];
  float sumZ = 0.0f, sumX = 0.0f, S = 0.0f;
#pragma unroll
  for (int k = 0; k < NCLS; k++) {
    distZ[k] = sqrtf(sZ[k]);
    float sc = expf(-distZ[k]) + 1e-10f;
    phiZ[k] = sc;
    sumZ += sc;
    float dx = sqrtf(sX[k]);
    float scx = expf(-dx) + 1e-10f;
    S += logf(scx);
    sumX += scx;
  }
  S -= 7.0f * logf(sumX);
  const float invZ = 1.0f / sumZ;
#pragma unroll
  for (int k = 0; k < NCLS; k++) phiZ[k] *= invZ;

  const int yc = y[wid];
  float w[NCLS];
  float W = 0.0f;
#pragma unroll
  for (int k = 0; k < NCLS; k++) {
    float diff = phiZ[k] * S - logf(Q[yc * NCLS + k]);
    w[k] = phiZ[k] * diff;
    W += w[k];
  }
  float v0 = 0.0f, v1 = 0.0f;
#pragma unroll
  for (int k = 0; k < NCLS; k++) {
    float coef = -(w[k] - W * phiZ[k]) / (distZ[k] + 1e-12f);
    v0 += coef * (z0 - ca[k * 128 + lane]);
    v1 += coef * (z1 - ca[k * 128 + 64 + lane]);
  }
  vbuf[(size_t)wid * 128 + lane] = v0;
  vbuf[(size_t)wid * 128 + 64 + lane] = v1;

  if (lane < NCLS) {
    // avoid runtime-indexed register array (goes to scratch): unrolled select
    float pv = (lane == 0) ? phiZ[0]
              : (lane == 1) ? phiZ[1]
              : (lane == 2) ? phiZ[2]
              : (lane == 3) ? phiZ[3]
              : (lane == 4) ? phiZ[4]
              : (lane == 5) ? phiZ[5]
                            : phiZ[6];
    phi_out[(size_t)wid * NCLS + lane] = pv;
  }
}

// ---------------------------------------------------------------------------
// K10: h2 = elu(Z0) @ W2   [N,64]
// ---------------------------------------------------------------------------
__global__ __launch_bounds__(256) void gemm2_kernel(
    const float* __restrict__ Z0out, const float* __restrict__ W2,
    float* __restrict__ h2, int n) {
  __shared__ float w2s[128 * 64];  // 32KB
  __shared__ float xs[16 * 128];   // 8KB
  const int t = threadIdx.x;
  for (int i = t; i < 128 * 64; i += 256) w2s[i] = W2[i];
  const int n0 = blockIdx.x * 16;
  for (int i = t; i < 16 * 128; i += 256) {
    int r = i >> 7, cc = i & 127;
    int gr = n0 + r;
    float zv = (gr < n) ? Z0out[(size_t)gr * 128 + cc] : 0.0f;
    xs[i] = (zv > 0.0f) ? zv : (expf(zv) - 1.0f);  // elu
  }
  __syncthreads();
  const int c = t & 63;
  const int rb = t >> 6;  // 0..3
  float acc[4] = {0.0f, 0.0f, 0.0f, 0.0f};
  for (int k = 0; k < 128; k++) {
    float wv = w2s[k * 64 + c];
#pragma unroll
    for (int i = 0; i < 4; i++) acc[i] += xs[(rb + 4 * i) * 128 + k] * wv;
  }
#pragma unroll
  for (int i = 0; i < 4; i++) {
    int gr = n0 + rb + 4 * i;
    if (gr < n) h2[(size_t)gr * 64 + c] = acc[i];
  }
}

// ---------------------------------------------------------------------------
// K11: conv2 gather. One wave per dst node. Per edge: grad = v[src]·F0[dst]/N
// (64-lane butterfly dot), B1 = alpha - grad, sign-normalize, accumulate
// B1*h2[src]. Out = acc + b2.
// ---------------------------------------------------------------------------
__global__ __launch_bounds__(256) void conv2_kernel(
    const float* __restrict__ F0, const float* __restrict__ vbuf,
    const float* __restrict__ h2, const float* __restrict__ alpha,
    const int* __restrict__ rowptr, const int* __restrict__ esrc,
    const float* __restrict__ b2, float* __restrict__ outp, int n,
    float invN) {
  const int wid = (blockIdx.x * blockDim.x + threadIdx.x) >> 6;
  const int lane = threadIdx.x & 63;
  if (wid >= n) return;
  const int start = rowptr[wid];
  const int end = rowptr[wid + 1];
  const float f0 = F0[(size_t)wid * 128 + lane];
  const float f1 = F0[(size_t)wid * 128 + 64 + lane];
  float acc = 0.0f;
  for (int j = start; j < end; j++) {
    const int s = esrc[j];    // uniform across wave -> broadcast
    const float a = alpha[j];
    float p = vbuf[(size_t)s * 128 + lane] * f0 +
              vbuf[(size_t)s * 128 + 64 + lane] * f1;
    for (int m = 32; m; m >>= 1) p += __shfl_xor(p, m);
    const float B1 = a - p * invN;
    const float wgt = B1 / (fabsf(B1) + 1e-16f);
    acc += wgt * h2[(size_t)s * 64 + lane];
  }
  outp[(size_t)wid * 64 + lane] = acc + b2[lane];
}

// ---------------------------------------------------------------------------
extern "C" void kernel_launch(void* const* d_in, const int* in_sizes, int n_in,
                              void* d_out, int out_size, void* d_ws,
                              size_t ws_size, hipStream_t stream) {
  const float* x = (const float*)d_in[0];
  const int* ei = (const int*)d_in[1];
  const int* y = (const int*)d_in[2];
  const float* cb = (const float*)d_in[3];
  const float* Q = (const float*)d_in[4];
  const float* W1 = (const float*)d_in[5];
  const float* a_src = (const float*)d_in[6];
  const float* a_dst = (const float*)d_in[7];
  const float* b1 = (const float*)d_in[8];
  const float* W2 = (const float*)d_in[9];
  const float* b2 = (const float*)d_in[10];

  const int N = in_sizes[2];       // 100000
  const int E = in_sizes[1] / 2;   // 1600000
  const int* srcp = ei;
  const int* dstp = ei + E;

  // workspace layout
  float* F0 = (float*)d_ws;                    // N*128
  float* as_dot = F0 + (size_t)N * 128;        // N
  float* ad_dot = as_dot + N;                  // N
  float* alpha = ad_dot + N;                   // E
  float* vbuf = alpha + E;                     // N*128
  float* ca = vbuf + (size_t)N * 128;          // 7*128
  float* csum = ca + NCLS * 128;               // 7*128
  float* ccnt = csum + NCLS * 128;             // 7 (+pad)
  int* deg = (int*)(ccnt + 16);                // N
  int* rowptr = deg + N;                       // N+1
  int* cursor = rowptr + N + 1;                // N
  int* esrc = cursor + N;                      // E

  // outputs (concatenated): out[N,64], h2[N,64], Z0[N,128], phi_Z[N,7]
  float* out_o = (float*)d_out;
  float* h2_o = out_o + (size_t)N * 64;
  float* z0_o = h2_o + (size_t)N * 64;
  float* phi_o = z0_o + (size_t)N * 128;

  hipMemsetAsync(deg, 0, (size_t)N * sizeof(int), stream);
  hipMemsetAsync(csum, 0, (NCLS * 128 + 16) * sizeof(float), stream);

  gemm1_kernel<<<(N + 63) / 64, 256, 0, stream>>>(x, W1, F0, N);
  dots_kernel<<<(N + 3) / 4, 256, 0, stream>>>(F0, a_src, a_dst, as_dot,
                                               ad_dot, N);
  hist_kernel<<<(E + 255) / 256, 256, 0, stream>>>(dstp, deg, E);
  {
    int items = (N + 1023) / 1024;
    scan_kernel<<<1, 1024, 0, stream>>>(deg, rowptr, cursor, N, items);
  }
  scatter_kernel<<<(E + 255) / 256, 256, 0, stream>>>(srcp, dstp, cursor, esrc,
                                                      E);
  gat1_kernel<<<(N + 3) / 4, 256, 0, stream>>>(F0, as_dot, ad_dot, rowptr,
                                               esrc, b1, alpha, z0_o, N);
  centroid_sum_kernel<<<(N + CB_NODES - 1) / CB_NODES, 128, 0, stream>>>(
      z0_o, y, csum, ccnt, N);
  centroid_fin_kernel<<<NCLS, 128, 0, stream>>>(csum, ccnt, ca);
  phi_v_kernel<<<(N + 3) / 4, 256, 0, stream>>>(z0_o, x, ca, cb, Q, y, vbuf,
                                                phi_o, N);
  gemm2_kernel<<<(N + 15) / 16, 256, 0, stream>>>(z0_o, W2, h2_o, N);
  conv2_kernel<<<(N + 3) / 4, 256, 0, stream>>>(F0, vbuf, h2_o, alpha, rowptr,
                                                esrc, b2, out_o, N,
                                                1.0f / (float)N);
}

// Round 2
// 1105.395 us; speedup vs baseline: 1.3551x; 1.3551x over previous
//
#include <hip/hip_runtime.h>
#include <hip/hip_bf16.h>
#include <math.h>

// Problem constants (feature dims fixed by the reference).
#define IN_DIM 128
#define HID_DIM 128
#define OUT_DIM 64
#define NCLS 7

// ---------------------------------------------------------------------------
// K1: F0 = x @ W1   [N,128] = [N,128]@[128,128]
// ---------------------------------------------------------------------------
__global__ __launch_bounds__(256) void gemm1_kernel(
    const float* __restrict__ x, const float* __restrict__ W1,
    float* __restrict__ F0, int n) {
  __shared__ float xs[64 * 128];  // 32KB
  const int t = threadIdx.x;
  const int n0 = blockIdx.x * 64;

  for (int i = t; i < 64 * 128; i += 256) {
    int r = i >> 7, cc = i & 127;
    int gr = n0 + r;
    xs[i] = (gr < n) ? x[(size_t)gr * 128 + cc] : 0.0f;
  }
  __syncthreads();

  const int c = t & 127;
  const int half = t >> 7;  // 0 or 1
  float acc[32];
#pragma unroll
  for (int i = 0; i < 32; i++) acc[i] = 0.0f;

  for (int k0 = 0; k0 < 128; k0 += 8) {
    float w[8];
#pragma unroll
    for (int kk = 0; kk < 8; kk++) w[kk] = W1[(size_t)(k0 + kk) * 128 + c];
#pragma unroll
    for (int i = 0; i < 32; i++) {
      const int r = half + 2 * i;
#pragma unroll
      for (int kk = 0; kk < 8; kk++) acc[i] += xs[r * 128 + k0 + kk] * w[kk];
    }
  }
#pragma unroll
  for (int i = 0; i < 32; i++) {
    int gr = n0 + half + 2 * i;
    if (gr < n) F0[(size_t)gr * 128 + c] = acc[i];
  }
}

// ---------------------------------------------------------------------------
// K2: per-node attention dots
// ---------------------------------------------------------------------------
__global__ __launch_bounds__(256) void dots_kernel(
    const float* __restrict__ F0, const float* __restrict__ a_src,
    const float* __restrict__ a_dst, float* __restrict__ as_dot,
    float* __restrict__ ad_dot, int n) {
  const int wid = (blockIdx.x * blockDim.x + threadIdx.x) >> 6;
  const int lane = threadIdx.x & 63;
  if (wid >= n) return;
  float f0 = F0[(size_t)wid * 128 + lane];
  float f1 = F0[(size_t)wid * 128 + 64 + lane];
  float s = f0 * a_src[lane] + f1 * a_src[64 + lane];
  float d = f0 * a_dst[lane] + f1 * a_dst[64 + lane];
  for (int m = 32; m; m >>= 1) {
    s += __shfl_xor(s, m);
    d += __shfl_xor(d, m);
  }
  if (lane == 0) {
    as_dot[wid] = s;
    ad_dot[wid] = d;
  }
}

// ---------------------------------------------------------------------------
// K3: degree histogram over dst
// ---------------------------------------------------------------------------
__global__ __launch_bounds__(256) void hist_kernel(const int* __restrict__ dst,
                                                   int* __restrict__ deg,
                                                   int e) {
  int i = blockIdx.x * blockDim.x + threadIdx.x;
  if (i < e) atomicAdd(&deg[dst[i]], 1);
}

// ---------------------------------------------------------------------------
// K4a/b/c: multi-block exclusive scan of deg -> rowptr (+cursor copy).
// 1024 elements per block (256 threads x 4).
// ---------------------------------------------------------------------------
__global__ __launch_bounds__(256) void scan1_kernel(const int* __restrict__ deg,
                                                    int* __restrict__ bsum,
                                                    int n) {
  __shared__ int lds[256];
  const int b = blockIdx.x, t = threadIdx.x;
  const int base = b * 1024 + t * 4;
  int s = 0;
#pragma unroll
  for (int u = 0; u < 4; u++) {
    int i = base + u;
    if (i < n) s += deg[i];
  }
  lds[t] = s;
  __syncthreads();
  for (int off = 128; off; off >>= 1) {
    if (t < off) lds[t] += lds[t + off];
    __syncthreads();
  }
  if (t == 0) bsum[b] = lds[0];
}

__global__ __launch_bounds__(1024) void scan2_kernel(
    const int* __restrict__ bsum, int* __restrict__ boff,
    int* __restrict__ rowptr, int nb, int n) {
  __shared__ int lds[1024];
  const int t = threadIdx.x;
  int v = (t < nb) ? bsum[t] : 0;
  lds[t] = v;
  __syncthreads();
  for (int off = 1; off < 1024; off <<= 1) {
    int add = (t >= off) ? lds[t - off] : 0;
    __syncthreads();
    lds[t] += add;
    __syncthreads();
  }
  if (t < nb) boff[t] = lds[t] - v;  // exclusive
  if (t == nb - 1) rowptr[n] = lds[t];
}

__global__ __launch_bounds__(256) void scan3_kernel(
    const int* __restrict__ deg, const int* __restrict__ boff,
    int* __restrict__ rowptr, int* __restrict__ cursor, int n) {
  __shared__ int lds[256];
  const int b = blockIdx.x, t = threadIdx.x;
  const int base = b * 1024 + t * 4;
  int v[4];
  int s = 0;
#pragma unroll
  for (int u = 0; u < 4; u++) {
    int i = base + u;
    v[u] = (i < n) ? deg[i] : 0;
    s += v[u];
  }
  lds[t] = s;
  __syncthreads();
  for (int off = 1; off < 256; off <<= 1) {
    int add = (t >= off) ? lds[t - off] : 0;
    __syncthreads();
    lds[t] += add;
    __syncthreads();
  }
  int run = boff[b] + lds[t] - s;  // exclusive prefix for this thread
#pragma unroll
  for (int u = 0; u < 4; u++) {
    int i = base + u;
    if (i < n) {
      rowptr[i] = run;
      cursor[i] = run;
      run += v[u];
    }
  }
}

// ---------------------------------------------------------------------------
// K5: scatter edges into CSR slots (store src per slot).
// ---------------------------------------------------------------------------
__global__ __launch_bounds__(256) void scatter_kernel(
    const int* __restrict__ src, const int* __restrict__ dst,
    int* __restrict__ cursor, int* __restrict__ esrc, int e) {
  int i = blockIdx.x * blockDim.x + threadIdx.x;
  if (i < e) {
    int pos = atomicAdd(&cursor[dst[i]], 1);
    esrc[pos] = src[i];
  }
}

// ---------------------------------------------------------------------------
// K6: GAT layer 1 (segment softmax + gather). One wave per dst node.
// ---------------------------------------------------------------------------
__global__ __launch_bounds__(256) void gat1_kernel(
    const float* __restrict__ F0, const float* __restrict__ as_dot,
    const float* __restrict__ ad_dot, const int* __restrict__ rowptr,
    const int* __restrict__ esrc, const float* __restrict__ b1,
    float* __restrict__ alpha, float* __restrict__ Z0out, int n) {
  const int wid = (blockIdx.x * blockDim.x + threadIdx.x) >> 6;
  const int lane = threadIdx.x & 63;
  if (wid >= n) return;
  const int start = rowptr[wid];
  const int end = rowptr[wid + 1];
  const float adn = ad_dot[wid];

  float lmax = -INFINITY;
  for (int j = start + lane; j < end; j += 64) {
    int s = esrc[j];
    float z = as_dot[s] + adn;
    z = (z > 0.0f) ? z : 0.2f * z;
    lmax = fmaxf(lmax, z);
  }
  for (int m = 32; m; m >>= 1) lmax = fmaxf(lmax, __shfl_xor(lmax, m));

  float lsum = 0.0f;
  for (int j = start + lane; j < end; j += 64) {
    int s = esrc[j];
    float z = as_dot[s] + adn;
    z = (z > 0.0f) ? z : 0.2f * z;
    lsum += expf(z - lmax);
  }
  for (int m = 32; m; m >>= 1) lsum += __shfl_xor(lsum, m);
  const float inv = 1.0f / (lsum + 1e-16f);

  float acc0 = 0.0f, acc1 = 0.0f;
  for (int base = start; base < end; base += 64) {
    const int len = min(64, end - base);
    float aj = 0.0f;
    int sj = 0;
    if (lane < len) {
      int j = base + lane;
      sj = esrc[j];
      float z = as_dot[sj] + adn;
      z = (z > 0.0f) ? z : 0.2f * z;
      aj = expf(z - lmax) * inv;
      alpha[j] = aj;
    }
    for (int q = 0; q < len; q++) {
      float a = __shfl(aj, q);
      int s = __shfl(sj, q);
      acc0 += a * F0[(size_t)s * 128 + lane];
      acc1 += a * F0[(size_t)s * 128 + 64 + lane];
    }
  }
  Z0out[(size_t)wid * 128 + lane] = acc0 + b1[lane];
  Z0out[(size_t)wid * 128 + 64 + lane] = acc1 + b1[64 + lane];
}

// ---------------------------------------------------------------------------
// K7: centroid partial sums — stage 1. 256 blocks x 128 threads; per-class
// register accumulation over a contiguous node chunk; no atomic contention
// (partials to scratch). Stage 2 reduces the 256 partials.
// ---------------------------------------------------------------------------
#define CNB 256
__global__ __launch_bounds__(128) void centroid_partial_kernel(
    const float* __restrict__ Z0out, const int* __restrict__ y,
    float* __restrict__ partial, float* __restrict__ ccnt, int n, int per) {
  const int t = threadIdx.x;  // feature 0..127
  const int b = blockIdx.x;
  const int n0 = b * per;
  const int n1 = min(n0 + per, n);
  float a[NCLS];
#pragma unroll
  for (int k = 0; k < NCLS; k++) a[k] = 0.0f;
  int cnt[NCLS];
#pragma unroll
  for (int k = 0; k < NCLS; k++) cnt[k] = 0;

#pragma unroll 4
  for (int i = n0; i < n1; i++) {
    const int c = y[i];
    const float v = Z0out[(size_t)i * 128 + t];
#pragma unroll
    for (int k = 0; k < NCLS; k++) a[k] += (c == k) ? v : 0.0f;
    if (t == 0) {
#pragma unroll
      for (int k = 0; k < NCLS; k++) cnt[k] += (c == k) ? 1 : 0;
    }
  }
#pragma unroll
  for (int k = 0; k < NCLS; k++)
    partial[((size_t)b * NCLS + k) * 128 + t] = a[k];
  if (t == 0) {
#pragma unroll
    for (int k = 0; k < NCLS; k++) atomicAdd(&ccnt[k], (float)cnt[k]);
  }
}

__global__ __launch_bounds__(1024) void centroid_reduce_kernel(
    const float* __restrict__ partial, const float* __restrict__ ccnt,
    float* __restrict__ ca, int nb) {
  const int t = threadIdx.x;
  if (t >= NCLS * 128) return;
  float s = 0.0f;
#pragma unroll 8
  for (int b = 0; b < nb; b++) s += partial[(size_t)b * (NCLS * 128) + t];
  ca[t] = s / (ccnt[t >> 7] + 1e-12f);
}

// ---------------------------------------------------------------------------
// K9: phi_Z, phi_X, S, diff, v. One wave per node.
// ---------------------------------------------------------------------------
__global__ __launch_bounds__(256) void phi_v_kernel(
    const float* __restrict__ Z0out, const float* __restrict__ x,
    const float* __restrict__ ca, const float* __restrict__ cb,
    const float* __restrict__ Q, const int* __restrict__ y,
    float* __restrict__ vbuf, float* __restrict__ phi_out, int n) {
  const int wid = (blockIdx.x * blockDim.x + threadIdx.x) >> 6;
  const int lane = threadIdx.x & 63;
  if (wid >= n) return;
  const float z0 = Z0out[(size_t)wid * 128 + lane];
  const float z1 = Z0out[(size_t)wid * 128 + 64 + lane];
  const float x0 = x[(size_t)wid * 128 + lane];
  const float x1 = x[(size_t)wid * 128 + 64 + lane];

  float sZ[NCLS], sX[NCLS];
#pragma unroll
  for (int k = 0; k < NCLS; k++) {
    float d0 = z0 - ca[k * 128 + lane];
    float d1 = z1 - ca[k * 128 + 64 + lane];
    sZ[k] = d0 * d0 + d1 * d1;
    float e0 = x0 - cb[k * 128 + lane];
    float e1 = x1 - cb[k * 128 + 64 + lane];
    sX[k] = e0 * e0 + e1 * e1;
  }
  for (int m = 32; m; m >>= 1) {
#pragma unroll
    for (int k = 0; k < NCLS; k++) {
      sZ[k] += __shfl_xor(sZ[k], m);
      sX[k] += __shfl_xor(sX[k], m);
    }
  }
  float distZ[NCLS], phiZ[NCLS];
  float sumZ = 0.0f, sumX = 0.0f, S = 0.0f;
#pragma unroll
  for (int k = 0; k < NCLS; k++) {
    distZ[k] = sqrtf(sZ[k]);
    float sc = expf(-distZ[k]) + 1e-10f;
    phiZ[k] = sc;
    sumZ += sc;
    float dx = sqrtf(sX[k]);
    float scx = expf(-dx) + 1e-10f;
    S += logf(scx);
    sumX += scx;
  }
  S -= 7.0f * logf(sumX);
  const float invZ = 1.0f / sumZ;
#pragma unroll
  for (int k = 0; k < NCLS; k++) phiZ[k] *= invZ;

  const int yc = y[wid];
  float w[NCLS];
  float W = 0.0f;
#pragma unroll
  for (int k = 0; k < NCLS; k++) {
    float diff = phiZ[k] * S - logf(Q[yc * NCLS + k]);
    w[k] = phiZ[k] * diff;
    W += w[k];
  }
  float v0 = 0.0f, v1 = 0.0f;
#pragma unroll
  for (int k = 0; k < NCLS; k++) {
    float coef = -(w[k] - W * phiZ[k]) / (distZ[k] + 1e-12f);
    v0 += coef * (z0 - ca[k * 128 + lane]);
    v1 += coef * (z1 - ca[k * 128 + 64 + lane]);
  }
  vbuf[(size_t)wid * 128 + lane] = v0;
  vbuf[(size_t)wid * 128 + 64 + lane] = v1;

  if (lane < NCLS) {
    float pv = (lane == 0) ? phiZ[0]
              : (lane == 1) ? phiZ[1]
              : (lane == 2) ? phiZ[2]
              : (lane == 3) ? phiZ[3]
              : (lane == 4) ? phiZ[4]
              : (lane == 5) ? phiZ[5]
                            : phiZ[6];
    phi_out[(size_t)wid * NCLS + lane] = pv;
  }
}

// ---------------------------------------------------------------------------
// K10: h2 = elu(Z0) @ W2   [N,64]
// ---------------------------------------------------------------------------
__global__ __launch_bounds__(256) void gemm2_kernel(
    const float* __restrict__ Z0out, const float* __restrict__ W2,
    float* __restrict__ h2, int n) {
  __shared__ float w2s[128 * 64];  // 32KB
  __shared__ float xs[16 * 128];   // 8KB
  const int t = threadIdx.x;
  for (int i = t; i < 128 * 64; i += 256) w2s[i] = W2[i];
  const int n0 = blockIdx.x * 16;
  for (int i = t; i < 16 * 128; i += 256) {
    int r = i >> 7, cc = i & 127;
    int gr = n0 + r;
    float zv = (gr < n) ? Z0out[(size_t)gr * 128 + cc] : 0.0f;
    xs[i] = (zv > 0.0f) ? zv : (expf(zv) - 1.0f);  // elu
  }
  __syncthreads();
  const int c = t & 63;
  const int rb = t >> 6;  // 0..3
  float acc[4] = {0.0f, 0.0f, 0.0f, 0.0f};
  for (int k = 0; k < 128; k++) {
    float wv = w2s[k * 64 + c];
#pragma unroll
    for (int i = 0; i < 4; i++) acc[i] += xs[(rb + 4 * i) * 128 + k] * wv;
  }
#pragma unroll
  for (int i = 0; i < 4; i++) {
    int gr = n0 + rb + 4 * i;
    if (gr < n) h2[(size_t)gr * 64 + c] = acc[i];
  }
}

// ---------------------------------------------------------------------------
// K11: conv2 gather. One wave per dst node.
// ---------------------------------------------------------------------------
__global__ __launch_bounds__(256) void conv2_kernel(
    const float* __restrict__ F0, const float* __restrict__ vbuf,
    const float* __restrict__ h2, const float* __restrict__ alpha,
    const int* __restrict__ rowptr, const int* __restrict__ esrc,
    const float* __restrict__ b2, float* __restrict__ outp, int n,
    float invN) {
  const int wid = (blockIdx.x * blockDim.x + threadIdx.x) >> 6;
  const int lane = threadIdx.x & 63;
  if (wid >= n) return;
  const int start = rowptr[wid];
  const int end = rowptr[wid + 1];
  const float f0 = F0[(size_t)wid * 128 + lane];
  const float f1 = F0[(size_t)wid * 128 + 64 + lane];
  float acc = 0.0f;
  for (int j = start; j < end; j++) {
    const int s = esrc[j];
    const float a = alpha[j];
    float p = vbuf[(size_t)s * 128 + lane] * f0 +
              vbuf[(size_t)s * 128 + 64 + lane] * f1;
    for (int m = 32; m; m >>= 1) p += __shfl_xor(p, m);
    const float B1 = a - p * invN;
    const float wgt = B1 / (fabsf(B1) + 1e-16f);
    acc += wgt * h2[(size_t)s * 64 + lane];
  }
  outp[(size_t)wid * 64 + lane] = acc + b2[lane];
}

// ---------------------------------------------------------------------------
extern "C" void kernel_launch(void* const* d_in, const int* in_sizes, int n_in,
                              void* d_out, int out_size, void* d_ws,
                              size_t ws_size, hipStream_t stream) {
  const float* x = (const float*)d_in[0];
  const int* ei = (const int*)d_in[1];
  const int* y = (const int*)d_in[2];
  const float* cb = (const float*)d_in[3];
  const float* Q = (const float*)d_in[4];
  const float* W1 = (const float*)d_in[5];
  const float* a_src = (const float*)d_in[6];
  const float* a_dst = (const float*)d_in[7];
  const float* b1 = (const float*)d_in[8];
  const float* W2 = (const float*)d_in[9];
  const float* b2 = (const float*)d_in[10];

  const int N = in_sizes[2];       // 100000
  const int E = in_sizes[1] / 2;   // 1600000
  const int* srcp = ei;
  const int* dstp = ei + E;

  // workspace layout
  float* F0 = (float*)d_ws;                    // N*128
  float* as_dot = F0 + (size_t)N * 128;        // N
  float* ad_dot = as_dot + N;                  // N
  float* alpha = ad_dot + N;                   // E
  float* vbuf = alpha + E;                     // N*128 (phi_v output; scratch
                                               // aliased below before phi_v)
  float* ca = vbuf + (size_t)N * 128;          // 7*128
  float* ccnt = ca + NCLS * 128;               // 16
  int* deg = (int*)(ccnt + 16);                // N
  int* rowptr = deg + N;                       // N+1
  int* cursor = rowptr + N + 1;                // N
  int* esrc = cursor + N;                      // E

  // scratch aliased into vbuf (all consumers finish before phi_v writes vbuf)
  float* partial = vbuf;                       // CNB*7*128 = 229376 floats
  int* bsum = (int*)(vbuf + (size_t)CNB * NCLS * 128);  // 1024
  int* boff = bsum + 1024;                               // 1024

  // outputs (concatenated): out[N,64], h2[N,64], Z0[N,128], phi_Z[N,7]
  float* out_o = (float*)d_out;
  float* h2_o = out_o + (size_t)N * 64;
  float* z0_o = h2_o + (size_t)N * 64;
  float* phi_o = z0_o + (size_t)N * 128;

  hipMemsetAsync(deg, 0, (size_t)N * sizeof(int), stream);
  hipMemsetAsync(ccnt, 0, 16 * sizeof(float), stream);

  gemm1_kernel<<<(N + 63) / 64, 256, 0, stream>>>(x, W1, F0, N);
  dots_kernel<<<(N + 3) / 4, 256, 0, stream>>>(F0, a_src, a_dst, as_dot,
                                               ad_dot, N);
  hist_kernel<<<(E + 255) / 256, 256, 0, stream>>>(dstp, deg, E);
  {
    const int nb = (N + 1023) / 1024;  // 98 for N=100000 (<=1024 supported)
    scan1_kernel<<<nb, 256, 0, stream>>>(deg, bsum, N);
    scan2_kernel<<<1, 1024, 0, stream>>>(bsum, boff, rowptr, nb, N);
    scan3_kernel<<<nb, 256, 0, stream>>>(deg, boff, rowptr, cursor, N);
  }
  scatter_kernel<<<(E + 255) / 256, 256, 0, stream>>>(srcp, dstp, cursor, esrc,
                                                      E);
  gat1_kernel<<<(N + 3) / 4, 256, 0, stream>>>(F0, as_dot, ad_dot, rowptr,
                                               esrc, b1, alpha, z0_o, N);
  {
    const int per = (N + CNB - 1) / CNB;  // nodes per block
    centroid_partial_kernel<<<CNB, 128, 0, stream>>>(z0_o, y, partial, ccnt, N,
                                                     per);
    centroid_reduce_kernel<<<1, 1024, 0, stream>>>(partial, ccnt, ca, CNB);
  }
  phi_v_kernel<<<(N + 3) / 4, 256, 0, stream>>>(z0_o, x, ca, cb, Q, y, vbuf,
                                                phi_o, N);
  gemm2_kernel<<<(N + 15) / 16, 256, 0, stream>>>(z0_o, W2, h2_o, N);
  conv2_kernel<<<(N + 3) / 4, 256, 0, stream>>>(F0, vbuf, h2_o, alpha, rowptr,
                                                esrc, b2, out_o, N,
                                                1.0f / (float)N);
}

// Round 3
// 1030.164 us; speedup vs baseline: 1.4541x; 1.0730x over previous
//
#include <hip/hip_runtime.h>
#include <hip/hip_bf16.h>
#include <math.h>

// Problem constants (feature dims fixed by the reference).
#define IN_DIM 128
#define HID_DIM 128
#define OUT_DIM 64
#define NCLS 7

// ---------------------------------------------------------------------------
// K1: F0 = x @ W1   [N,128] = [N,128]@[128,128]
// ---------------------------------------------------------------------------
__global__ __launch_bounds__(256) void gemm1_kernel(
    const float* __restrict__ x, const float* __restrict__ W1,
    float* __restrict__ F0, int n) {
  __shared__ float xs[64 * 128];  // 32KB
  const int t = threadIdx.x;
  const int n0 = blockIdx.x * 64;

  for (int i = t; i < 64 * 128; i += 256) {
    int r = i >> 7, cc = i & 127;
    int gr = n0 + r;
    xs[i] = (gr < n) ? x[(size_t)gr * 128 + cc] : 0.0f;
  }
  __syncthreads();

  const int c = t & 127;
  const int half = t >> 7;  // 0 or 1
  float acc[32];
#pragma unroll
  for (int i = 0; i < 32; i++) acc[i] = 0.0f;

  for (int k0 = 0; k0 < 128; k0 += 8) {
    float w[8];
#pragma unroll
    for (int kk = 0; kk < 8; kk++) w[kk] = W1[(size_t)(k0 + kk) * 128 + c];
#pragma unroll
    for (int i = 0; i < 32; i++) {
      const int r = half + 2 * i;
#pragma unroll
      for (int kk = 0; kk < 8; kk++) acc[i] += xs[r * 128 + k0 + kk] * w[kk];
    }
  }
#pragma unroll
  for (int i = 0; i < 32; i++) {
    int gr = n0 + half + 2 * i;
    if (gr < n) F0[(size_t)gr * 128 + c] = acc[i];
  }
}

// ---------------------------------------------------------------------------
// K2: per-node attention dots
// ---------------------------------------------------------------------------
__global__ __launch_bounds__(256) void dots_kernel(
    const float* __restrict__ F0, const float* __restrict__ a_src,
    const float* __restrict__ a_dst, float* __restrict__ as_dot,
    float* __restrict__ ad_dot, int n) {
  const int wid = (blockIdx.x * blockDim.x + threadIdx.x) >> 6;
  const int lane = threadIdx.x & 63;
  if (wid >= n) return;
  float f0 = F0[(size_t)wid * 128 + lane];
  float f1 = F0[(size_t)wid * 128 + 64 + lane];
  float s = f0 * a_src[lane] + f1 * a_src[64 + lane];
  float d = f0 * a_dst[lane] + f1 * a_dst[64 + lane];
  for (int m = 32; m; m >>= 1) {
    s += __shfl_xor(s, m);
    d += __shfl_xor(d, m);
  }
  if (lane == 0) {
    as_dot[wid] = s;
    ad_dot[wid] = d;
  }
}

// ---------------------------------------------------------------------------
// K3: degree histogram over dst
// ---------------------------------------------------------------------------
__global__ __launch_bounds__(256) void hist_kernel(const int* __restrict__ dst,
                                                   int* __restrict__ deg,
                                                   int e) {
  int i = blockIdx.x * blockDim.x + threadIdx.x;
  if (i < e) atomicAdd(&deg[dst[i]], 1);
}

// ---------------------------------------------------------------------------
// K4a/b/c: multi-block exclusive scan of deg -> rowptr (+cursor copy).
// ---------------------------------------------------------------------------
__global__ __launch_bounds__(256) void scan1_kernel(const int* __restrict__ deg,
                                                    int* __restrict__ bsum,
                                                    int n) {
  __shared__ int lds[256];
  const int b = blockIdx.x, t = threadIdx.x;
  const int base = b * 1024 + t * 4;
  int s = 0;
#pragma unroll
  for (int u = 0; u < 4; u++) {
    int i = base + u;
    if (i < n) s += deg[i];
  }
  lds[t] = s;
  __syncthreads();
  for (int off = 128; off; off >>= 1) {
    if (t < off) lds[t] += lds[t + off];
    __syncthreads();
  }
  if (t == 0) bsum[b] = lds[0];
}

__global__ __launch_bounds__(1024) void scan2_kernel(
    const int* __restrict__ bsum, int* __restrict__ boff,
    int* __restrict__ rowptr, int nb, int n) {
  __shared__ int lds[1024];
  const int t = threadIdx.x;
  int v = (t < nb) ? bsum[t] : 0;
  lds[t] = v;
  __syncthreads();
  for (int off = 1; off < 1024; off <<= 1) {
    int add = (t >= off) ? lds[t - off] : 0;
    __syncthreads();
    lds[t] += add;
    __syncthreads();
  }
  if (t < nb) boff[t] = lds[t] - v;  // exclusive
  if (t == nb - 1) rowptr[n] = lds[t];
}

__global__ __launch_bounds__(256) void scan3_kernel(
    const int* __restrict__ deg, const int* __restrict__ boff,
    int* __restrict__ rowptr, int* __restrict__ cursor, int n) {
  __shared__ int lds[256];
  const int b = blockIdx.x, t = threadIdx.x;
  const int base = b * 1024 + t * 4;
  int v[4];
  int s = 0;
#pragma unroll
  for (int u = 0; u < 4; u++) {
    int i = base + u;
    v[u] = (i < n) ? deg[i] : 0;
    s += v[u];
  }
  lds[t] = s;
  __syncthreads();
  for (int off = 1; off < 256; off <<= 1) {
    int add = (t >= off) ? lds[t - off] : 0;
    __syncthreads();
    lds[t] += add;
    __syncthreads();
  }
  int run = boff[b] + lds[t] - s;
#pragma unroll
  for (int u = 0; u < 4; u++) {
    int i = base + u;
    if (i < n) {
      rowptr[i] = run;
      cursor[i] = run;
      run += v[u];
    }
  }
}

// ---------------------------------------------------------------------------
// K5: scatter edges into CSR slots (store src per slot).
// ---------------------------------------------------------------------------
__global__ __launch_bounds__(256) void scatter_kernel(
    const int* __restrict__ src, const int* __restrict__ dst,
    int* __restrict__ cursor, int* __restrict__ esrc, int e) {
  int i = blockIdx.x * blockDim.x + threadIdx.x;
  if (i < e) {
    int pos = atomicAdd(&cursor[dst[i]], 1);
    esrc[pos] = src[i];
  }
}

// ---------------------------------------------------------------------------
// K6: GAT layer 1. One wave per dst node. Softmax passes 64-lane strided;
// gather pass: 4 edges concurrently, 16 lanes each (lane holds 8 dims).
// ---------------------------------------------------------------------------
__global__ __launch_bounds__(256) void gat1_kernel(
    const float* __restrict__ F0, const float* __restrict__ as_dot,
    const float* __restrict__ ad_dot, const int* __restrict__ rowptr,
    const int* __restrict__ esrc, const float* __restrict__ b1,
    float* __restrict__ alpha, float* __restrict__ Z0out, int n) {
  const int wid = (blockIdx.x * blockDim.x + threadIdx.x) >> 6;
  const int lane = threadIdx.x & 63;
  if (wid >= n) return;
  const int start = rowptr[wid];
  const int end = rowptr[wid + 1];
  const float adn = ad_dot[wid];

  // pass A: max
  float lmax = -INFINITY;
  for (int j = start + lane; j < end; j += 64) {
    int s = esrc[j];
    float z = as_dot[s] + adn;
    z = (z > 0.0f) ? z : 0.2f * z;
    lmax = fmaxf(lmax, z);
  }
  for (int m = 32; m; m >>= 1) lmax = fmaxf(lmax, __shfl_xor(lmax, m));

  // pass B: sum of exp
  float lsum = 0.0f;
  for (int j = start + lane; j < end; j += 64) {
    int s = esrc[j];
    float z = as_dot[s] + adn;
    z = (z > 0.0f) ? z : 0.2f * z;
    lsum += expf(z - lmax);
  }
  for (int m = 32; m; m >>= 1) lsum += __shfl_xor(lsum, m);
  const float inv = 1.0f / (lsum + 1e-16f);

  // pass C: alpha + feature gather. group g (0..3) owns edge base+g;
  // lane l (0..15) owns dims [8l, 8l+8).
  const int g = lane >> 4;
  const int l = lane & 15;
  float4 accA = {0.f, 0.f, 0.f, 0.f};
  float4 accB = {0.f, 0.f, 0.f, 0.f};
  for (int base = start; base < end; base += 4) {
    const int j = base + g;
    const bool act = (j < end);
    const int sj = act ? esrc[j] : 0;
    float aj = 0.0f;
    if (act) {
      float z = as_dot[sj] + adn;
      z = (z > 0.0f) ? z : 0.2f * z;
      aj = expf(z - lmax) * inv;
      if (l == 0) alpha[j] = aj;
    }
    const float4 vA = *(const float4*)&F0[(size_t)sj * 128 + l * 8];
    const float4 vB = *(const float4*)&F0[(size_t)sj * 128 + l * 8 + 4];
    accA.x += aj * vA.x; accA.y += aj * vA.y;
    accA.z += aj * vA.z; accA.w += aj * vA.w;
    accB.x += aj * vB.x; accB.y += aj * vB.y;
    accB.z += aj * vB.z; accB.w += aj * vB.w;
  }
  // merge the 4 groups (dims d live in lanes {l, l+16, l+32, l+48})
#pragma unroll
  for (int m = 16; m <= 32; m <<= 1) {
    accA.x += __shfl_xor(accA.x, m); accA.y += __shfl_xor(accA.y, m);
    accA.z += __shfl_xor(accA.z, m); accA.w += __shfl_xor(accA.w, m);
    accB.x += __shfl_xor(accB.x, m); accB.y += __shfl_xor(accB.y, m);
    accB.z += __shfl_xor(accB.z, m); accB.w += __shfl_xor(accB.w, m);
  }
  if (g == 0) {
    const float4 bA = *(const float4*)&b1[l * 8];
    const float4 bB = *(const float4*)&b1[l * 8 + 4];
    float4 oA = {accA.x + bA.x, accA.y + bA.y, accA.z + bA.z, accA.w + bA.w};
    float4 oB = {accB.x + bB.x, accB.y + bB.y, accB.z + bB.z, accB.w + bB.w};
    *(float4*)&Z0out[(size_t)wid * 128 + l * 8] = oA;
    *(float4*)&Z0out[(size_t)wid * 128 + l * 8 + 4] = oB;
  }
}

// ---------------------------------------------------------------------------
// K7: centroid partial sums (stage 1) + reduce (stage 2).
// ---------------------------------------------------------------------------
#define CNB 256
__global__ __launch_bounds__(128) void centroid_partial_kernel(
    const float* __restrict__ Z0out, const int* __restrict__ y,
    float* __restrict__ partial, float* __restrict__ ccnt, int n, int per) {
  const int t = threadIdx.x;  // feature 0..127
  const int b = blockIdx.x;
  const int n0 = b * per;
  const int n1 = min(n0 + per, n);
  float a[NCLS];
#pragma unroll
  for (int k = 0; k < NCLS; k++) a[k] = 0.0f;
  int cnt[NCLS];
#pragma unroll
  for (int k = 0; k < NCLS; k++) cnt[k] = 0;

#pragma unroll 4
  for (int i = n0; i < n1; i++) {
    const int c = y[i];
    const float v = Z0out[(size_t)i * 128 + t];
#pragma unroll
    for (int k = 0; k < NCLS; k++) a[k] += (c == k) ? v : 0.0f;
    if (t == 0) {
#pragma unroll
      for (int k = 0; k < NCLS; k++) cnt[k] += (c == k) ? 1 : 0;
    }
  }
#pragma unroll
  for (int k = 0; k < NCLS; k++)
    partial[((size_t)b * NCLS + k) * 128 + t] = a[k];
  if (t == 0) {
#pragma unroll
    for (int k = 0; k < NCLS; k++) atomicAdd(&ccnt[k], (float)cnt[k]);
  }
}

__global__ __launch_bounds__(1024) void centroid_reduce_kernel(
    const float* __restrict__ partial, const float* __restrict__ ccnt,
    float* __restrict__ ca, int nb) {
  const int t = threadIdx.x;
  if (t >= NCLS * 128) return;
  float s = 0.0f;
#pragma unroll 8
  for (int b = 0; b < nb; b++) s += partial[(size_t)b * (NCLS * 128) + t];
  ca[t] = s / (ccnt[t >> 7] + 1e-12f);
}

// ---------------------------------------------------------------------------
// K9: phi_Z, phi_X, S, diff, v. One wave per node.
// ---------------------------------------------------------------------------
__global__ __launch_bounds__(256) void phi_v_kernel(
    const float* __restrict__ Z0out, const float* __restrict__ x,
    const float* __restrict__ ca, const float* __restrict__ cb,
    const float* __restrict__ Q, const int* __restrict__ y,
    float* __restrict__ vbuf, float* __restrict__ phi_out, int n) {
  const int wid = (blockIdx.x * blockDim.x + threadIdx.x) >> 6;
  const int lane = threadIdx.x & 63;
  if (wid >= n) return;
  const float z0 = Z0out[(size_t)wid * 128 + lane];
  const float z1 = Z0out[(size_t)wid * 128 + 64 + lane];
  const float x0 = x[(size_t)wid * 128 + lane];
  const float x1 = x[(size_t)wid * 128 + 64 + lane];

  float sZ[NCLS], sX[NCLS];
#pragma unroll
  for (int k = 0; k < NCLS; k++) {
    float d0 = z0 - ca[k * 128 + lane];
    float d1 = z1 - ca[k * 128 + 64 + lane];
    sZ[k] = d0 * d0 + d1 * d1;
    float e0 = x0 - cb[k * 128 + lane];
    float e1 = x1 - cb[k * 128 + 64 + lane];
    sX[k] = e0 * e0 + e1 * e1;
  }
  for (int m = 32; m; m >>= 1) {
#pragma unroll
    for (int k = 0; k < NCLS; k++) {
      sZ[k] += __shfl_xor(sZ[k], m);
      sX[k] += __shfl_xor(sX[k], m);
    }
  }
  float distZ[NCLS], phiZ[NCLS];
  float sumZ = 0.0f, sumX = 0.0f, S = 0.0f;
#pragma unroll
  for (int k = 0; k < NCLS; k++) {
    distZ[k] = sqrtf(sZ[k]);
    float sc = expf(-distZ[k]) + 1e-10f;
    phiZ[k] = sc;
    sumZ += sc;
    float dx = sqrtf(sX[k]);
    float scx = expf(-dx) + 1e-10f;
    S += logf(scx);
    sumX += scx;
  }
  S -= 7.0f * logf(sumX);
  const float invZ = 1.0f / sumZ;
#pragma unroll
  for (int k = 0; k < NCLS; k++) phiZ[k] *= invZ;

  const int yc = y[wid];
  float w[NCLS];
  float W = 0.0f;
#pragma unroll
  for (int k = 0; k < NCLS; k++) {
    float diff = phiZ[k] * S - logf(Q[yc * NCLS + k]);
    w[k] = phiZ[k] * diff;
    W += w[k];
  }
  float v0 = 0.0f, v1 = 0.0f;
#pragma unroll
  for (int k = 0; k < NCLS; k++) {
    float coef = -(w[k] - W * phiZ[k]) / (distZ[k] + 1e-12f);
    v0 += coef * (z0 - ca[k * 128 + lane]);
    v1 += coef * (z1 - ca[k * 128 + 64 + lane]);
  }
  vbuf[(size_t)wid * 128 + lane] = v0;
  vbuf[(size_t)wid * 128 + 64 + lane] = v1;

  if (lane < NCLS) {
    float pv = (lane == 0) ? phiZ[0]
              : (lane == 1) ? phiZ[1]
              : (lane == 2) ? phiZ[2]
              : (lane == 3) ? phiZ[3]
              : (lane == 4) ? phiZ[4]
              : (lane == 5) ? phiZ[5]
                            : phiZ[6];
    phi_out[(size_t)wid * NCLS + lane] = pv;
  }
}

// ---------------------------------------------------------------------------
// K10: h2 = elu(Z0) @ W2   [N,64]
// ---------------------------------------------------------------------------
__global__ __launch_bounds__(256) void gemm2_kernel(
    const float* __restrict__ Z0out, const float* __restrict__ W2,
    float* __restrict__ h2, int n) {
  __shared__ float w2s[128 * 64];  // 32KB
  __shared__ float xs[16 * 128];   // 8KB
  const int t = threadIdx.x;
  for (int i = t; i < 128 * 64; i += 256) w2s[i] = W2[i];
  const int n0 = blockIdx.x * 16;
  for (int i = t; i < 16 * 128; i += 256) {
    int r = i >> 7, cc = i & 127;
    int gr = n0 + r;
    float zv = (gr < n) ? Z0out[(size_t)gr * 128 + cc] : 0.0f;
    xs[i] = (zv > 0.0f) ? zv : (expf(zv) - 1.0f);  // elu
  }
  __syncthreads();
  const int c = t & 63;
  const int rb = t >> 6;  // 0..3
  float acc[4] = {0.0f, 0.0f, 0.0f, 0.0f};
  for (int k = 0; k < 128; k++) {
    float wv = w2s[k * 64 + c];
#pragma unroll
    for (int i = 0; i < 4; i++) acc[i] += xs[(rb + 4 * i) * 128 + k] * wv;
  }
#pragma unroll
  for (int i = 0; i < 4; i++) {
    int gr = n0 + rb + 4 * i;
    if (gr < n) h2[(size_t)gr * 64 + c] = acc[i];
  }
}

// ---------------------------------------------------------------------------
// K11: conv2 gather. One wave per dst node; 4 edges concurrently (16 lanes
// each). Dot v[src]·F0[dst] in-group; then 64-lane h2 accumulation.
// ---------------------------------------------------------------------------
__global__ __launch_bounds__(256) void conv2_kernel(
    const float* __restrict__ F0, const float* __restrict__ vbuf,
    const float* __restrict__ h2, const float* __restrict__ alpha,
    const int* __restrict__ rowptr, const int* __restrict__ esrc,
    const float* __restrict__ b2, float* __restrict__ outp, int n,
    float invN) {
  const int wid = (blockIdx.x * blockDim.x + threadIdx.x) >> 6;
  const int lane = threadIdx.x & 63;
  if (wid >= n) return;
  const int start = rowptr[wid];
  const int end = rowptr[wid + 1];
  const int g = lane >> 4;
  const int l = lane & 15;
  const float4 fA = *(const float4*)&F0[(size_t)wid * 128 + l * 8];
  const float4 fB = *(const float4*)&F0[(size_t)wid * 128 + l * 8 + 4];
  float acc = 0.0f;  // output feature = lane
  for (int base = start; base < end; base += 4) {
    const int j = base + g;
    const bool act = (j < end);
    const int sj = act ? esrc[j] : 0;
    const float a = act ? alpha[j] : 0.0f;
    const float4 vA = *(const float4*)&vbuf[(size_t)sj * 128 + l * 8];
    const float4 vB = *(const float4*)&vbuf[(size_t)sj * 128 + l * 8 + 4];
    float p = vA.x * fA.x + vA.y * fA.y + vA.z * fA.z + vA.w * fA.w +
              vB.x * fB.x + vB.y * fB.y + vB.z * fB.z + vB.w * fB.w;
    p += __shfl_xor(p, 1);
    p += __shfl_xor(p, 2);
    p += __shfl_xor(p, 4);
    p += __shfl_xor(p, 8);
    const float B1 = a - p * invN;
    const float w = act ? (B1 / (fabsf(B1) + 1e-16f)) : 0.0f;
#pragma unroll
    for (int g2 = 0; g2 < 4; g2++) {
      const float wg = __shfl(w, g2 * 16);
      const int sg = __shfl(sj, g2 * 16);
      acc += wg * h2[(size_t)sg * 64 + lane];
    }
  }
  outp[(size_t)wid * 64 + lane] = acc + b2[lane];
}

// ---------------------------------------------------------------------------
extern "C" void kernel_launch(void* const* d_in, const int* in_sizes, int n_in,
                              void* d_out, int out_size, void* d_ws,
                              size_t ws_size, hipStream_t stream) {
  const float* x = (const float*)d_in[0];
  const int* ei = (const int*)d_in[1];
  const int* y = (const int*)d_in[2];
  const float* cb = (const float*)d_in[3];
  const float* Q = (const float*)d_in[4];
  const float* W1 = (const float*)d_in[5];
  const float* a_src = (const float*)d_in[6];
  const float* a_dst = (const float*)d_in[7];
  const float* b1 = (const float*)d_in[8];
  const float* W2 = (const float*)d_in[9];
  const float* b2 = (const float*)d_in[10];

  const int N = in_sizes[2];       // 100000
  const int E = in_sizes[1] / 2;   // 1600000
  const int* srcp = ei;
  const int* dstp = ei + E;

  // workspace layout
  float* F0 = (float*)d_ws;                    // N*128
  float* as_dot = F0 + (size_t)N * 128;        // N
  float* ad_dot = as_dot + N;                  // N
  float* alpha = ad_dot + N;                   // E
  float* vbuf = alpha + E;                     // N*128
  float* ca = vbuf + (size_t)N * 128;          // 7*128
  float* ccnt = ca + NCLS * 128;               // 16
  int* deg = (int*)(ccnt + 16);                // N
  int* rowptr = deg + N;                       // N+1
  int* cursor = rowptr + N + 1;                // N
  int* esrc = cursor + N;                      // E

  // scratch aliased into vbuf (all consumers finish before phi_v writes vbuf)
  float* partial = vbuf;                       // CNB*7*128 floats
  int* bsum = (int*)(vbuf + (size_t)CNB * NCLS * 128);  // 1024
  int* boff = bsum + 1024;                               // 1024

  // outputs (concatenated): out[N,64], h2[N,64], Z0[N,128], phi_Z[N,7]
  float* out_o = (float*)d_out;
  float* h2_o = out_o + (size_t)N * 64;
  float* z0_o = h2_o + (size_t)N * 64;
  float* phi_o = z0_o + (size_t)N * 128;

  hipMemsetAsync(deg, 0, (size_t)N * sizeof(int), stream);
  hipMemsetAsync(ccnt, 0, 16 * sizeof(float), stream);

  gemm1_kernel<<<(N + 63) / 64, 256, 0, stream>>>(x, W1, F0, N);
  dots_kernel<<<(N + 3) / 4, 256, 0, stream>>>(F0, a_src, a_dst, as_dot,
                                               ad_dot, N);
  hist_kernel<<<(E + 255) / 256, 256, 0, stream>>>(dstp, deg, E);
  {
    const int nb = (N + 1023) / 1024;
    scan1_kernel<<<nb, 256, 0, stream>>>(deg, bsum, N);
    scan2_kernel<<<1, 1024, 0, stream>>>(bsum, boff, rowptr, nb, N);
    scan3_kernel<<<nb, 256, 0, stream>>>(deg, boff, rowptr, cursor, N);
  }
  scatter_kernel<<<(E + 255) / 256, 256, 0, stream>>>(srcp, dstp, cursor, esrc,
                                                      E);
  gat1_kernel<<<(N + 3) / 4, 256, 0, stream>>>(F0, as_dot, ad_dot, rowptr,
                                               esrc, b1, alpha, z0_o, N);
  {
    const int per = (N + CNB - 1) / CNB;
    centroid_partial_kernel<<<CNB, 128, 0, stream>>>(z0_o, y, partial, ccnt, N,
                                                     per);
    centroid_reduce_kernel<<<1, 1024, 0, stream>>>(partial, ccnt, ca, CNB);
  }
  phi_v_kernel<<<(N + 3) / 4, 256, 0, stream>>>(z0_o, x, ca, cb, Q, y, vbuf,
                                                phi_o, N);
  gemm2_kernel<<<(N + 15) / 16, 256, 0, stream>>>(z0_o, W2, h2_o, N);
  conv2_kernel<<<(N + 3) / 4, 256, 0, stream>>>(F0, vbuf, h2_o, alpha, rowptr,
                                                esrc, b2, out_o, N,
                                                1.0f / (float)N);
}